// Round 1
// baseline (495.933 us; speedup 1.0000x reference)
//
#include <hip/hip_runtime.h>
#include <stdint.h>

// ---- problem constants (fixed shapes) ----
#define BTOT   256      // B*T frames
#define LX     197      // tokens incl CLS
#define CDIM   768
#define CADIM  384
#define TFR    8
#define HHH    14
#define WWW    14
#define LM1    196      // L-1
#define MTOT   50176    // BTOT*LM1

typedef unsigned short u16;
typedef short          bf16x8 __attribute__((ext_vector_type(8)));
typedef unsigned short u16x4  __attribute__((ext_vector_type(4)));
typedef unsigned short u16x8  __attribute__((ext_vector_type(8)));
typedef float          f32x4  __attribute__((ext_vector_type(4)));

static __device__ __forceinline__ u16 f2bf(float f) {
  union { float f; uint32_t u; } v; v.f = f;
  uint32_t u = v.u;
  return (u16)((u + 0x7FFFu + ((u >> 16) & 1u)) >> 16);  // RNE
}
static __device__ __forceinline__ float bf2f(u16 h) {
  union { uint32_t u; float f; } v; v.u = ((uint32_t)h) << 16;
  return v.f;
}

// ---------------- prep: x fp32 -> bf16 ----------------
__global__ void prep_x(const float4* __restrict__ x, u16x4* __restrict__ xb, int nvec) {
  int stride = gridDim.x * blockDim.x;
  for (int i = blockIdx.x * blockDim.x + threadIdx.x; i < nvec; i += stride) {
    float4 v = x[i];
    u16x4 o;
    o[0] = f2bf(v.x); o[1] = f2bf(v.y); o[2] = f2bf(v.z); o[3] = f2bf(v.w);
    xb[i] = o;
  }
}

// ---------------- prep: weights bf16 + conv_w transpose ----------------
__global__ void prep_w(const float* __restrict__ W1, const float* __restrict__ W2,
                       const float* __restrict__ cw, u16* __restrict__ w1b,
                       u16* __restrict__ w2b, float* __restrict__ cwT) {
  int i = blockIdx.x * blockDim.x + threadIdx.x;
  if (i < CADIM * CDIM) { w1b[i] = f2bf(W1[i]); w2b[i] = f2bf(W2[i]); }
  if (i < CADIM * 27) {
    int a = i / 27; int tap = i - a * 27;
    cwT[tap * CADIM + a] = cw[i];        // [27][384] channel-contiguous
  }
}

// ---------------- CLS rows: out = x ----------------
__global__ void cls_copy(const float4* __restrict__ x, float4* __restrict__ out) {
  int i = blockIdx.x * blockDim.x + threadIdx.x;   // 256 rows * 192 vec4
  int bt = i / 192;
  int c  = i - bt * 192;
  int idx = bt * (LX * CDIM / 4) + c;              // row 0 of frame bt
  out[idx] = x[idx];
}

// ---------------- fc1: h1[m, a] = x[m,:] . W1[a,:] + b1[a] ----------------
#define BK  64
#define LDK 72   // padded LDS leading dim (144 B rows -> 2-way bank alias, free)

__global__ __launch_bounds__(256) void fc1_gemm(
    const u16* __restrict__ A,    // xb [256*197*768] bf16
    const u16* __restrict__ Bw,   // w1b [384][768] bf16 (N x K row-major)
    const float* __restrict__ bias,
    u16* __restrict__ Hout)       // [50176][384] bf16
{
  __shared__ __align__(16) u16 As[128 * LDK];
  __shared__ __align__(16) u16 Bs[128 * LDK];
  const int tid = threadIdx.x;
  const int m0 = blockIdx.x * 128;
  const int n0 = blockIdx.y * 128;
  const int lane = tid & 63;
  const int wv = tid >> 6;
  const int wm = (wv & 1) * 64;
  const int wn = (wv >> 1) * 64;
  const int lm = lane & 15;
  const int lk = lane >> 4;

  f32x4 acc[4][4];
#pragma unroll
  for (int i = 0; i < 4; i++)
#pragma unroll
    for (int j = 0; j < 4; j++) acc[i][j] = (f32x4)0.0f;

  // per-thread staging rows (chunk = it*256 + tid; 8 chunks of 16B per row)
  int arow_off[4], brow_off[4];
#pragma unroll
  for (int it = 0; it < 4; ++it) {
    int chunk = it * 256 + tid;
    int row = chunk >> 3;
    int tok = m0 + row;
    int bt = tok / LM1;
    int l = tok - bt * LM1;
    arow_off[it] = (bt * LX + 1 + l) * CDIM;   // skip CLS
    brow_off[it] = (n0 + row) * CDIM;
  }

  for (int k0 = 0; k0 < CDIM; k0 += BK) {
#pragma unroll
    for (int it = 0; it < 4; ++it) {
      int chunk = it * 256 + tid;
      int row = chunk >> 3;
      int cc = chunk & 7;
      *(bf16x8*)&As[row * LDK + cc * 8] = *(const bf16x8*)(A + arow_off[it] + k0 + cc * 8);
      *(bf16x8*)&Bs[row * LDK + cc * 8] = *(const bf16x8*)(Bw + brow_off[it] + k0 + cc * 8);
    }
    __syncthreads();
#pragma unroll
    for (int kk = 0; kk < BK; kk += 32) {
      bf16x8 af[4], bfr[4];
#pragma unroll
      for (int i = 0; i < 4; i++)
        af[i] = *(const bf16x8*)&As[(wm + i * 16 + lm) * LDK + kk + lk * 8];
#pragma unroll
      for (int j = 0; j < 4; j++)
        bfr[j] = *(const bf16x8*)&Bs[(wn + j * 16 + lm) * LDK + kk + lk * 8];
#pragma unroll
      for (int i = 0; i < 4; i++)
#pragma unroll
        for (int j = 0; j < 4; j++)
          acc[i][j] = __builtin_amdgcn_mfma_f32_16x16x32_bf16(af[i], bfr[j], acc[i][j], 0, 0, 0);
    }
    __syncthreads();
  }

#pragma unroll
  for (int i = 0; i < 4; i++) {
    int rbase = m0 + wm + i * 16 + lk * 4;
#pragma unroll
    for (int j = 0; j < 4; j++) {
      int col = n0 + wn + j * 16 + lm;
      float bv = bias[col];
#pragma unroll
      for (int r = 0; r < 4; r++)
        Hout[(rbase + r) * CADIM + col] = f2bf(acc[i][j][r] + bv);
    }
  }
}

// ---------------- depthwise 3x3x3 conv, channels-last ----------------
__global__ __launch_bounds__(256) void dwconv(
    const u16* __restrict__ h1, const float* __restrict__ cwT,
    const float* __restrict__ cb, u16* __restrict__ h2)
{
  int idx = blockIdx.x * blockDim.x + threadIdx.x;   // < MTOT*48
  int tok = idx / 48;
  int cg = idx - tok * 48;
  int a0 = cg * 8;
  int bt = tok / LM1;
  int l = tok - bt * LM1;
  int t = bt & 7;
  int b = bt >> 3;
  int h = l / 14;
  int w = l - h * 14;

  float acc[8];
#pragma unroll
  for (int c = 0; c < 8; c++) acc[c] = cb[a0 + c];

#pragma unroll
  for (int dt = -1; dt <= 1; ++dt) {
    int tt = t + dt;
    if (tt < 0 || tt >= TFR) continue;
#pragma unroll
    for (int dh = -1; dh <= 1; ++dh) {
      int hh = h + dh;
      if (hh < 0 || hh >= HHH) continue;
#pragma unroll
      for (int dw = -1; dw <= 1; ++dw) {
        int ww = w + dw;
        if (ww < 0 || ww >= WWW) continue;
        int ntok = (b * TFR + tt) * LM1 + hh * 14 + ww;
        bf16x8 v = *(const bf16x8*)(h1 + ntok * CADIM + a0);
        int tap = (dt + 1) * 9 + (dh + 1) * 3 + (dw + 1);
        const float* wp = cwT + tap * CADIM + a0;
#pragma unroll
        for (int c = 0; c < 8; c++)
          acc[c] += bf2f((u16)v[c]) * wp[c];
      }
    }
  }
  u16x8 o;
#pragma unroll
  for (int c = 0; c < 8; c++) o[c] = f2bf(acc[c]);
  *(u16x8*)(h2 + tok * CADIM + a0) = o;
}

// ---------------- fc2 + residual: out = x + h2 . W2^T + b2 ----------------
__global__ __launch_bounds__(256) void fc2_gemm(
    const u16* __restrict__ A,    // h2 [50176][384] bf16
    const u16* __restrict__ Bw,   // w2b [768][384] bf16 (N x K row-major)
    const float* __restrict__ bias,
    const float* __restrict__ x,
    float* __restrict__ out)
{
  __shared__ __align__(16) u16 As[128 * LDK];
  __shared__ __align__(16) u16 Bs[128 * LDK];
  const int tid = threadIdx.x;
  const int m0 = blockIdx.x * 128;
  const int n0 = blockIdx.y * 128;
  const int lane = tid & 63;
  const int wv = tid >> 6;
  const int wm = (wv & 1) * 64;
  const int wn = (wv >> 1) * 64;
  const int lm = lane & 15;
  const int lk = lane >> 4;

  f32x4 acc[4][4];
#pragma unroll
  for (int i = 0; i < 4; i++)
#pragma unroll
    for (int j = 0; j < 4; j++) acc[i][j] = (f32x4)0.0f;

  int arow_off[4], brow_off[4];
#pragma unroll
  for (int it = 0; it < 4; ++it) {
    int chunk = it * 256 + tid;
    int row = chunk >> 3;
    arow_off[it] = (m0 + row) * CADIM;
    brow_off[it] = (n0 + row) * CADIM;
  }

  for (int k0 = 0; k0 < CADIM; k0 += BK) {
#pragma unroll
    for (int it = 0; it < 4; ++it) {
      int chunk = it * 256 + tid;
      int row = chunk >> 3;
      int cc = chunk & 7;
      *(bf16x8*)&As[row * LDK + cc * 8] = *(const bf16x8*)(A + arow_off[it] + k0 + cc * 8);
      *(bf16x8*)&Bs[row * LDK + cc * 8] = *(const bf16x8*)(Bw + brow_off[it] + k0 + cc * 8);
    }
    __syncthreads();
#pragma unroll
    for (int kk = 0; kk < BK; kk += 32) {
      bf16x8 af[4], bfr[4];
#pragma unroll
      for (int i = 0; i < 4; i++)
        af[i] = *(const bf16x8*)&As[(wm + i * 16 + lm) * LDK + kk + lk * 8];
#pragma unroll
      for (int j = 0; j < 4; j++)
        bfr[j] = *(const bf16x8*)&Bs[(wn + j * 16 + lm) * LDK + kk + lk * 8];
#pragma unroll
      for (int i = 0; i < 4; i++)
#pragma unroll
        for (int j = 0; j < 4; j++)
          acc[i][j] = __builtin_amdgcn_mfma_f32_16x16x32_bf16(af[i], bfr[j], acc[i][j], 0, 0, 0);
    }
    __syncthreads();
  }

  // epilogue: residual add + bias, fp32 out (rows remapped past CLS)
#pragma unroll
  for (int i = 0; i < 4; i++) {
    int rbase = m0 + wm + i * 16 + lk * 4;
#pragma unroll
    for (int r = 0; r < 4; r++) {
      int tok = rbase + r;
      int bt = tok / LM1;
      int l = tok - bt * LM1;
      int orow = (bt * LX + 1 + l) * CDIM;
#pragma unroll
      for (int j = 0; j < 4; j++) {
        int col = n0 + wn + j * 16 + lm;
        out[orow + col] = x[orow + col] + acc[i][j][r] + bias[col];
      }
    }
  }
}

// ---------------- launch ----------------
extern "C" void kernel_launch(void* const* d_in, const int* in_sizes, int n_in,
                              void* d_out, int out_size, void* d_ws, size_t ws_size,
                              hipStream_t stream) {
  const float* x  = (const float*)d_in[0];
  const float* W1 = (const float*)d_in[1];
  const float* b1 = (const float*)d_in[2];
  const float* cw = (const float*)d_in[3];
  const float* cb = (const float*)d_in[4];
  const float* W2 = (const float*)d_in[5];
  const float* b2 = (const float*)d_in[6];
  float* out = (float*)d_out;

  char* ws = (char*)d_ws;
  u16*   xb  = (u16*)(ws + 0);              //  77,463,552 B
  u16*   w1b = (u16*)(ws + 77463552);       //     589,824 B
  u16*   w2b = (u16*)(ws + 78053376);       //     589,824 B
  float* cwT = (float*)(ws + 78643200);     //      41,472 B
  u16*   h1  = (u16*)(ws + 78684672);       //  38,535,168 B
  u16*   h2  = (u16*)(ws + 117219840);      //  38,535,168 B  (end 155,755,008)

  const int xelems = BTOT * LX * CDIM;      // 38,731,776

  prep_x  <<<2048, 256, 0, stream>>>((const float4*)x, (u16x4*)xb, xelems / 4);
  prep_w  <<<(CADIM * CDIM + 255) / 256, 256, 0, stream>>>(W1, W2, cw, w1b, w2b, cwT);
  cls_copy<<<(BTOT * 192) / 256, 256, 0, stream>>>((const float4*)x, (float4*)out);
  fc1_gemm<<<dim3(MTOT / 128, CADIM / 128), 256, 0, stream>>>(xb, w1b, b1, h1);
  dwconv  <<<(MTOT * 48) / 256, 256, 0, stream>>>(h1, cwT, cb, h2);
  fc2_gemm<<<dim3(MTOT / 128, CDIM / 128), 256, 0, stream>>>(h2, w2b, b2, x, out);
}

// Round 2
// 473.661 us; speedup vs baseline: 1.0470x; 1.0470x over previous
//
#include <hip/hip_runtime.h>
#include <stdint.h>

// ---- problem constants (fixed shapes) ----
#define BTOT   256      // B*T frames
#define LX     197      // tokens incl CLS
#define CDIM   768
#define CADIM  384
#define TFR    8
#define LM1    196      // L-1
#define MTOT   50176    // BTOT*LM1

typedef unsigned short u16;
typedef short          bf16x8 __attribute__((ext_vector_type(8)));
typedef unsigned short u16x4  __attribute__((ext_vector_type(4)));
typedef unsigned short u16x8  __attribute__((ext_vector_type(8)));
typedef float          f32x4  __attribute__((ext_vector_type(4)));

typedef const __attribute__((address_space(1))) void gvoid_t;
typedef __attribute__((address_space(3))) void       svoid_t;

static __device__ __forceinline__ u16 f2bf(float f) {
  union { float f; uint32_t u; } v; v.f = f;
  uint32_t u = v.u;
  return (u16)((u + 0x7FFFu + ((u >> 16) & 1u)) >> 16);  // RNE
}
static __device__ __forceinline__ float bf2f(u16 h) {
  union { uint32_t u; float f; } v; v.u = ((uint32_t)h) << 16;
  return v.f;
}

// ---------------- prep: x fp32 -> bf16, fused CLS-row copy ----------------
__global__ void prep_x(const float4* __restrict__ x, u16x4* __restrict__ xb,
                       float4* __restrict__ out, int nvec) {
  int stride = gridDim.x * blockDim.x;
  for (int i = blockIdx.x * blockDim.x + threadIdx.x; i < nvec; i += stride) {
    float4 v = x[i];
    u16x4 o;
    o[0] = f2bf(v.x); o[1] = f2bf(v.y); o[2] = f2bf(v.z); o[3] = f2bf(v.w);
    xb[i] = o;
    int rem = i % 37824;          // 197*768/4 vec4s per frame
    if (rem < 192) out[i] = v;    // CLS row: out = x
  }
}

// ---------------- prep: weights bf16 + conv_w transpose ----------------
__global__ void prep_w(const float* __restrict__ W1, const float* __restrict__ W2,
                       const float* __restrict__ cw, u16* __restrict__ w1b,
                       u16* __restrict__ w2b, float* __restrict__ cwT) {
  int i = blockIdx.x * blockDim.x + threadIdx.x;
  if (i < CADIM * CDIM) { w1b[i] = f2bf(W1[i]); w2b[i] = f2bf(W2[i]); }
  if (i < CADIM * 27) {
    int a = i / 27; int tap = i - a * 27;
    cwT[tap * CADIM + a] = cw[i];        // [27][384] channel-contiguous
  }
}

// ======================================================================
// GEMM cores: 128x128 tile, BK=64, global_load_lds(16B) staging with XOR
// chunk swizzle: LDS slot s of row r holds global chunk (s ^ (r&7)).
// Rows are unpadded 64 elems (128 B); swizzle makes ds_read_b128 frag
// reads land on 8 distinct 4-bank windows -> 2-way alias (free, m136).
// ======================================================================

// ---------------- fc1: h1[m, a] = x[m,:] . W1[a,:] + b1[a] ----------------
__global__ __launch_bounds__(256) void fc1_gemm(
    const u16* __restrict__ A,    // xb bf16
    const u16* __restrict__ Bw,   // w1b [384][768] bf16 (N x K row-major)
    const float* __restrict__ bias,
    u16* __restrict__ Hout)       // [50176][384] bf16
{
  __shared__ __align__(16) u16 As[128 * 64];
  __shared__ __align__(16) u16 Bs[128 * 64];
  const int tid  = threadIdx.x;
  const int lane = tid & 63;
  const int wave = tid >> 6;
  const int m0 = blockIdx.x * 128;
  const int n0 = blockIdx.y * 128;
  const int lm = lane & 15;
  const int lk = lane >> 4;
  const int wm = (wave & 1) * 64;
  const int wn = (wave >> 1) * 64;

  // staging: wave fills rows [wave*32, wave*32+32); instr s covers 8 rows.
  // lane -> row = wave*32 + s*8 + (lane>>3), LDS slot = lane&7.
  const int srow = lane >> 3;                 // == row & 7
  const int cch  = (lane & 7) ^ srow;         // global chunk to fetch
  size_t aoff[4], boff[4];
  u16 *asdst[4], *bsdst[4];
#pragma unroll
  for (int s = 0; s < 4; ++s) {
    int row = wave * 32 + s * 8 + srow;
    int tok = m0 + row;
    int bt = tok / LM1;
    int l = tok - bt * LM1;
    aoff[s] = (size_t)(bt * LX + 1 + l) * CDIM + cch * 8;   // skip CLS
    boff[s] = (size_t)(n0 + row) * CDIM + cch * 8;
    asdst[s] = As + (wave * 32 + s * 8) * 64;
    bsdst[s] = Bs + (wave * 32 + s * 8) * 64;
  }
  const int r7  = lm & 7;
  const int sw0 = ((lk    ) ^ r7) << 3;   // kk=0  chunk = lk
  const int sw1 = ((lk + 4) ^ r7) << 3;   // kk=32 chunk = lk+4

  f32x4 acc[4][4];
#pragma unroll
  for (int i = 0; i < 4; i++)
#pragma unroll
    for (int j = 0; j < 4; j++) acc[i][j] = (f32x4)0.0f;

  for (int k0 = 0; k0 < CDIM; k0 += 64) {
#pragma unroll
    for (int s = 0; s < 4; ++s) {
      __builtin_amdgcn_global_load_lds((gvoid_t*)(A + aoff[s] + k0),
                                       (svoid_t*)asdst[s], 16, 0, 0);
      __builtin_amdgcn_global_load_lds((gvoid_t*)(Bw + boff[s] + k0),
                                       (svoid_t*)bsdst[s], 16, 0, 0);
    }
    __syncthreads();
    {
      bf16x8 af[4], bfr[4];
#pragma unroll
      for (int i = 0; i < 4; i++)
        af[i] = *(const bf16x8*)&As[(wm + i * 16 + lm) * 64 + sw0];
#pragma unroll
      for (int j = 0; j < 4; j++)
        bfr[j] = *(const bf16x8*)&Bs[(wn + j * 16 + lm) * 64 + sw0];
#pragma unroll
      for (int i = 0; i < 4; i++)
#pragma unroll
        for (int j = 0; j < 4; j++)
          acc[i][j] = __builtin_amdgcn_mfma_f32_16x16x32_bf16(af[i], bfr[j], acc[i][j], 0, 0, 0);
#pragma unroll
      for (int i = 0; i < 4; i++)
        af[i] = *(const bf16x8*)&As[(wm + i * 16 + lm) * 64 + sw1];
#pragma unroll
      for (int j = 0; j < 4; j++)
        bfr[j] = *(const bf16x8*)&Bs[(wn + j * 16 + lm) * 64 + sw1];
#pragma unroll
      for (int i = 0; i < 4; i++)
#pragma unroll
        for (int j = 0; j < 4; j++)
          acc[i][j] = __builtin_amdgcn_mfma_f32_16x16x32_bf16(af[i], bfr[j], acc[i][j], 0, 0, 0);
    }
    __syncthreads();
  }

#pragma unroll
  for (int i = 0; i < 4; i++) {
    int rbase = m0 + wm + i * 16 + lk * 4;
#pragma unroll
    for (int j = 0; j < 4; j++) {
      int col = n0 + wn + j * 16 + lm;
      float bv = bias[col];
#pragma unroll
      for (int r = 0; r < 4; r++)
        Hout[(rbase + r) * CADIM + col] = f2bf(acc[i][j][r] + bv);
    }
  }
}

// ---------------- depthwise 3x3x3 conv: 2x2 outputs/thread ----------------
__global__ __launch_bounds__(256) void dwconv(
    const u16* __restrict__ h1, const float* __restrict__ cwT,
    const float* __restrict__ cb, u16* __restrict__ h2)
{
  int idx = blockIdx.x * blockDim.x + threadIdx.x;   // < 256*49*48
  int cg = idx % 48;
  int rest = idx / 48;                 // frame*49 + hp*7 + wp
  int wp = rest % 7; rest /= 7;
  int hp = rest % 7; rest /= 7;        // rest = frame = b*8+t
  int t = rest & 7;
  int frame = rest;
  int a0 = cg * 8;
  int h0 = hp * 2, w0 = wp * 2;

  float acc[2][2][8];
#pragma unroll
  for (int c = 0; c < 8; ++c) {
    float bv = cb[a0 + c];
    acc[0][0][c] = bv; acc[0][1][c] = bv; acc[1][0][c] = bv; acc[1][1][c] = bv;
  }

#pragma unroll
  for (int dt = -1; dt <= 1; ++dt) {
    int tt = t + dt;
    if (tt < 0 || tt >= TFR) continue;
    // plane weights (9 taps x 8 ch) in registers, reused by all 4 outputs
    float wreg[9][8];
#pragma unroll
    for (int j = 0; j < 9; ++j) {
      const float* wp8 = cwT + ((dt + 1) * 9 + j) * CADIM + a0;
#pragma unroll
      for (int c = 0; c < 8; ++c) wreg[j][c] = wp8[c];
    }
    const u16* fbase = h1 + (size_t)(frame + dt) * LM1 * CADIM + a0;
#pragma unroll
    for (int ih = 0; ih < 4; ++ih) {
      int hh = h0 - 1 + ih;
      if (hh < 0 || hh >= 14) continue;
#pragma unroll
      for (int iw = 0; iw < 4; ++iw) {
        int ww = w0 - 1 + iw;
        if (ww < 0 || ww >= 14) continue;
        bf16x8 v = *(const bf16x8*)(fbase + (hh * 14 + ww) * CADIM);
        float vf[8];
#pragma unroll
        for (int c = 0; c < 8; ++c) vf[c] = bf2f((u16)v[c]);
#pragma unroll
        for (int oh = 0; oh < 2; ++oh) {
          if (ih - 1 - oh < -1 || ih - 1 - oh > 1) continue;   // compile-time
#pragma unroll
          for (int ow = 0; ow < 2; ++ow) {
            if (iw - 1 - ow < -1 || iw - 1 - ow > 1) continue; // compile-time
            int j = (ih - oh) * 3 + (iw - ow);                 // (dh+1)*3 + (dw+1)
#pragma unroll
            for (int c = 0; c < 8; ++c)
              acc[oh][ow][c] += vf[c] * wreg[j][c];
          }
        }
      }
    }
  }
  const size_t obase = (size_t)frame * LM1 * CADIM + a0;
#pragma unroll
  for (int oh = 0; oh < 2; ++oh)
#pragma unroll
    for (int ow = 0; ow < 2; ++ow) {
      u16x8 o;
#pragma unroll
      for (int c = 0; c < 8; ++c) o[c] = f2bf(acc[oh][ow][c]);
      *(u16x8*)(h2 + obase + ((size_t)(h0 + oh) * 14 + w0 + ow) * CADIM) = o;
    }
}

// ---------------- fc2 + residual: out = x + h2 . W2^T + b2 ----------------
__global__ __launch_bounds__(256) void fc2_gemm(
    const u16* __restrict__ A,    // h2 [50176][384] bf16
    const u16* __restrict__ Bw,   // w2b [768][384] bf16 (N x K row-major)
    const float* __restrict__ bias,
    const float* __restrict__ x,
    float* __restrict__ out)
{
  __shared__ __align__(16) u16 As[128 * 64];
  __shared__ __align__(16) u16 Bs[128 * 64];
  const int tid  = threadIdx.x;
  const int lane = tid & 63;
  const int wave = tid >> 6;
  const int m0 = blockIdx.x * 128;
  const int n0 = blockIdx.y * 128;
  const int lm = lane & 15;
  const int lk = lane >> 4;
  const int wm = (wave & 1) * 64;
  const int wn = (wave >> 1) * 64;

  const int srow = lane >> 3;
  const int cch  = (lane & 7) ^ srow;
  size_t aoff[4], boff[4];
  u16 *asdst[4], *bsdst[4];
#pragma unroll
  for (int s = 0; s < 4; ++s) {
    int row = wave * 32 + s * 8 + srow;
    aoff[s] = (size_t)(m0 + row) * CADIM + cch * 8;
    boff[s] = (size_t)(n0 + row) * CADIM + cch * 8;
    asdst[s] = As + (wave * 32 + s * 8) * 64;
    bsdst[s] = Bs + (wave * 32 + s * 8) * 64;
  }
  const int r7  = lm & 7;
  const int sw0 = ((lk    ) ^ r7) << 3;
  const int sw1 = ((lk + 4) ^ r7) << 3;

  f32x4 acc[4][4];
#pragma unroll
  for (int i = 0; i < 4; i++)
#pragma unroll
    for (int j = 0; j < 4; j++) acc[i][j] = (f32x4)0.0f;

  for (int k0 = 0; k0 < CADIM; k0 += 64) {
#pragma unroll
    for (int s = 0; s < 4; ++s) {
      __builtin_amdgcn_global_load_lds((gvoid_t*)(A + aoff[s] + k0),
                                       (svoid_t*)asdst[s], 16, 0, 0);
      __builtin_amdgcn_global_load_lds((gvoid_t*)(Bw + boff[s] + k0),
                                       (svoid_t*)bsdst[s], 16, 0, 0);
    }
    __syncthreads();
    {
      bf16x8 af[4], bfr[4];
#pragma unroll
      for (int i = 0; i < 4; i++)
        af[i] = *(const bf16x8*)&As[(wm + i * 16 + lm) * 64 + sw0];
#pragma unroll
      for (int j = 0; j < 4; j++)
        bfr[j] = *(const bf16x8*)&Bs[(wn + j * 16 + lm) * 64 + sw0];
#pragma unroll
      for (int i = 0; i < 4; i++)
#pragma unroll
        for (int j = 0; j < 4; j++)
          acc[i][j] = __builtin_amdgcn_mfma_f32_16x16x32_bf16(af[i], bfr[j], acc[i][j], 0, 0, 0);
#pragma unroll
      for (int i = 0; i < 4; i++)
        af[i] = *(const bf16x8*)&As[(wm + i * 16 + lm) * 64 + sw1];
#pragma unroll
      for (int j = 0; j < 4; j++)
        bfr[j] = *(const bf16x8*)&Bs[(wn + j * 16 + lm) * 64 + sw1];
#pragma unroll
      for (int i = 0; i < 4; i++)
#pragma unroll
        for (int j = 0; j < 4; j++)
          acc[i][j] = __builtin_amdgcn_mfma_f32_16x16x32_bf16(af[i], bfr[j], acc[i][j], 0, 0, 0);
    }
    __syncthreads();
  }

  // epilogue: residual add + bias, fp32 out (rows remapped past CLS)
#pragma unroll
  for (int i = 0; i < 4; i++) {
    int rbase = m0 + wm + i * 16 + lk * 4;
#pragma unroll
    for (int r = 0; r < 4; r++) {
      int tok = rbase + r;
      int bt = tok / LM1;
      int l = tok - bt * LM1;
      size_t orow = (size_t)(bt * LX + 1 + l) * CDIM;
#pragma unroll
      for (int j = 0; j < 4; j++) {
        int col = n0 + wn + j * 16 + lm;
        out[orow + col] = x[orow + col] + acc[i][j][r] + bias[col];
      }
    }
  }
}

// ---------------- launch ----------------
extern "C" void kernel_launch(void* const* d_in, const int* in_sizes, int n_in,
                              void* d_out, int out_size, void* d_ws, size_t ws_size,
                              hipStream_t stream) {
  const float* x  = (const float*)d_in[0];
  const float* W1 = (const float*)d_in[1];
  const float* b1 = (const float*)d_in[2];
  const float* cw = (const float*)d_in[3];
  const float* cb = (const float*)d_in[4];
  const float* W2 = (const float*)d_in[5];
  const float* b2 = (const float*)d_in[6];
  float* out = (float*)d_out;

  char* ws = (char*)d_ws;
  u16*   xb  = (u16*)(ws + 0);              //  77,463,552 B
  u16*   w1b = (u16*)(ws + 77463552);       //     589,824 B
  u16*   w2b = (u16*)(ws + 78053376);       //     589,824 B
  float* cwT = (float*)(ws + 78643200);     //      41,472 B
  u16*   h1  = (u16*)(ws + 78684672);       //  38,535,168 B
  u16*   h2  = (u16*)(ws + 117219840);      //  38,535,168 B

  const int xelems = BTOT * LX * CDIM;      // 38,731,776

  prep_x  <<<4096, 256, 0, stream>>>((const float4*)x, (u16x4*)xb, (float4*)out, xelems / 4);
  prep_w  <<<(CADIM * CDIM + 255) / 256, 256, 0, stream>>>(W1, W2, cw, w1b, w2b, cwT);
  fc1_gemm<<<dim3(MTOT / 128, CADIM / 128), 256, 0, stream>>>(xb, w1b, b1, h1);
  dwconv  <<<(BTOT * 49 * 48) / 256, 256, 0, stream>>>(h1, cwT, cb, h2);
  fc2_gemm<<<dim3(MTOT / 128, CDIM / 128), 256, 0, stream>>>(h2, w2b, b2, x, out);
}